// Round 5
// baseline (364.971 us; speedup 1.0000x reference)
//
#include <hip/hip_runtime.h>
#include <math.h>

#define NPTS 65536
#define DIM 64
#define NCODE 1024

typedef float f32x2 __attribute__((ext_vector_type(2)));
typedef float f32x4 __attribute__((ext_vector_type(4)));
typedef short bf16x8 __attribute__((ext_vector_type(8)));
typedef unsigned short u16x4 __attribute__((ext_vector_type(4)));

// output layout (flat float32 concat, reference return order)
#define OFF_LOSS 0ull
#define OFF_Q    1ull
#define OFF_PERP 4194305ull
#define OFF_ENC  4194306ull
#define OFF_IDX  71303170ull

__device__ __forceinline__ unsigned short bf16hi(float f) {
    unsigned u = __float_as_uint(f);
    unsigned r = u + 0x7FFFu + ((u >> 16) & 1u);   // RNE truncate to bf16
    return (unsigned short)(r >> 16);
}
__device__ __forceinline__ float bf16tof(unsigned short h) {
    return __uint_as_float(((unsigned)h) << 16);
}

// 8 consecutive fp32 (16B-aligned) -> hi/lo bf16x8
__device__ __forceinline__ void cvt8(const float* p, bf16x8& hi, bf16x8& lo) {
    float4 a = *(const float4*)p;
    float4 b = *(const float4*)(p + 4);
    float v[8] = {a.x, a.y, a.z, a.w, b.x, b.y, b.z, b.w};
#pragma unroll
    for (int i = 0; i < 8; ++i) {
        unsigned short h = bf16hi(v[i]);
        hi[i] = (short)h;
        lo[i] = (short)bf16hi(v[i] - bf16tof(h));
    }
}

// ---------------- emb fp32 -> (hi,lo) bf16 split, row-major (code, dim) ----------------
__global__ __launch_bounds__(256) void vq_ecvt(const float* __restrict__ emb,
                                               unsigned short* __restrict__ ehi,
                                               unsigned short* __restrict__ elo) {
    int t = blockIdx.x * 256 + threadIdx.x;        // one float4 each
    float4 v = ((const float4*)emb)[t];
    float vv[4] = {v.x, v.y, v.z, v.w};
    u16x4 hi, lo;
#pragma unroll
    for (int i = 0; i < 4; ++i) {
        unsigned short h = bf16hi(vv[i]);
        hi[i] = h;
        lo[i] = bf16hi(vv[i] - bf16tof(h));
    }
    *(u16x4*)(ehi + (size_t)t * 4) = hi;
    *(u16x4*)(elo + (size_t)t * 4) = lo;
}

// ---------------- e2[k] = sum_d emb[k][d]^2 ----------------
__global__ __launch_bounds__(256) void vq_e2(const float* __restrict__ emb,
                                             float* __restrict__ e2) {
    int k = blockIdx.x * 256 + threadIdx.x;
    if (k >= NCODE) return;
    const float4* e4 = (const float4*)(emb + (size_t)k * DIM);
    float s = 0.f;
#pragma unroll
    for (int i = 0; i < DIM / 4; ++i) {
        float4 v = e4[i];
        s += v.x * v.x + v.y * v.y + v.z * v.z + v.w * v.w;
    }
    e2[k] = s;
}

// ---------------- fused: MFMA distance argmin + q_ste + loss + one-hot ----------------
// Block = 4 waves, 64 points (one b,h w-row). fp32 x tile staged once in LDS
// (transposed (w,d)); bf16 hi/lo A-frags built from it in 2 pt-halves (keeps
// VGPR <=128 -> 4+ blocks/CU). Wave wv scans codes [256wv,256wv+256).
// dist = e2 - 2*(hi.hi + hi.lo + lo.hi) via mfma_f32_16x16x32_bf16.
// Packed-u64 (sortable dist, code) argmin: exact first-min tie-break.
// Epilogue reuses the fp32 LDS tile for the exact STE form + loss, then
// streams the 64x1024 one-hot block nontemporally.
__global__ __launch_bounds__(256, 4) void vq_fused(const float* __restrict__ in,
                                                   const unsigned short* __restrict__ ehi,
                                                   const unsigned short* __restrict__ elo,
                                                   const float* __restrict__ e2,
                                                   const float* __restrict__ emb,
                                                   float* __restrict__ out,
                                                   unsigned int* __restrict__ hist,
                                                   float* __restrict__ loss_acc) {
    __shared__ __align__(16) float lds_x[64][68];      // [w][d], 272B row stride
    __shared__ unsigned long long cand[4][64];
    __shared__ int s_idx[64];

    const int tid  = threadIdx.x;
    const int lane = tid & 63;
    const int wv   = __builtin_amdgcn_readfirstlane(tid >> 6);

    const int P0 = blockIdx.x * 64;
    const int b  = P0 >> 12;
    const int h  = (P0 >> 6) & 63;
    const float* base = in + (size_t)b * (DIM * 4096) + h * 64;

    // ---- prologue: 64x64 fp32 tile, coalesced load, transpose into LDS ----
    {
        int d  = tid >> 2;
        int wq = tid & 3;
        const float* rowp = base + (size_t)d * 4096 + wq * 16;
#pragma unroll
        for (int j = 0; j < 4; ++j) {
            float4 v = *(const float4*)(rowp + j * 4);
            int w0 = wq * 16 + j * 4;
            lds_x[w0 + 0][d] = v.x;
            lds_x[w0 + 1][d] = v.y;
            lds_x[w0 + 2][d] = v.z;
            lds_x[w0 + 3][d] = v.w;
        }
    }
    __syncthreads();

    const int m15 = lane & 15;
    const int g4  = lane >> 4;         // 0..3
    const int kb  = g4 * 8;            // A/B k-slice base
    const int c0w = wv * 256;          // this wave's code slice (ascending)

#pragma unroll 1
    for (int half = 0; half < 2; ++half) {
        bf16x8 Ahi[2][2], Alo[2][2];
#pragma unroll
        for (int pt = 0; pt < 2; ++pt) {
            int p = (half * 2 + pt) * 16 + m15;         // A row = lane&15
            cvt8(&lds_x[p][kb],      Ahi[pt][0], Alo[pt][0]);
            cvt8(&lds_x[p][kb + 32], Ahi[pt][1], Alo[pt][1]);
        }
        float best[2][4];
        int   bestk[2][4];
#pragma unroll
        for (int pt = 0; pt < 2; ++pt)
#pragma unroll
            for (int r = 0; r < 4; ++r) { best[pt][r] = INFINITY; bestk[pt][r] = 0; }

        for (int ct = 0; ct < 16; ++ct) {
            const int code = c0w + ct * 16 + m15;        // B col = lane&15
            const unsigned short* eh = ehi + (size_t)code * 64 + kb;
            const unsigned short* el = elo + (size_t)code * 64 + kb;
            bf16x8 Bhi0 = *(const bf16x8*)eh;
            bf16x8 Bhi1 = *(const bf16x8*)(eh + 32);
            bf16x8 Blo0 = *(const bf16x8*)el;
            bf16x8 Blo1 = *(const bf16x8*)(el + 32);
            float e2v = e2[code];

#pragma unroll
            for (int pt = 0; pt < 2; ++pt) {
                f32x4 acc = {0.f, 0.f, 0.f, 0.f};
                acc = __builtin_amdgcn_mfma_f32_16x16x32_bf16(Ahi[pt][0], Bhi0, acc, 0, 0, 0);
                acc = __builtin_amdgcn_mfma_f32_16x16x32_bf16(Ahi[pt][1], Bhi1, acc, 0, 0, 0);
                acc = __builtin_amdgcn_mfma_f32_16x16x32_bf16(Ahi[pt][0], Blo0, acc, 0, 0, 0);
                acc = __builtin_amdgcn_mfma_f32_16x16x32_bf16(Ahi[pt][1], Blo1, acc, 0, 0, 0);
                acc = __builtin_amdgcn_mfma_f32_16x16x32_bf16(Alo[pt][0], Bhi0, acc, 0, 0, 0);
                acc = __builtin_amdgcn_mfma_f32_16x16x32_bf16(Alo[pt][1], Bhi1, acc, 0, 0, 0);
#pragma unroll
                for (int r = 0; r < 4; ++r) {
                    float dist = fmaf(-2.0f, acc[r], e2v);
                    if (dist < best[pt][r]) { best[pt][r] = dist; bestk[pt][r] = code; }
                }
            }
        }

        // per-wave cross-lane argmin over the 16 cols, lexicographic (dist, code)
#pragma unroll
        for (int pt = 0; pt < 2; ++pt) {
#pragma unroll
            for (int r = 0; r < 4; ++r) {
                unsigned u = __float_as_uint(best[pt][r]);
                u = (u & 0x80000000u) ? ~u : (u | 0x80000000u);  // monotone f32->u32
                unsigned long long key = ((unsigned long long)u << 32) | (unsigned)bestk[pt][r];
#pragma unroll
                for (int sm = 1; sm < 16; sm <<= 1) {
                    unsigned long long o = __shfl_xor(key, sm, 16);
                    key = (o < key) ? o : key;
                }
                if (m15 == 0) cand[wv][(half * 2 + pt) * 16 + g4 * 4 + r] = key;
            }
        }
    }
    __syncthreads();

    if (tid < 64) {   // merge 4 wave-slices (ascending -> first-min tie-break)
        unsigned long long k0 = cand[0][tid];
#pragma unroll
        for (int s = 1; s < 4; ++s) {
            unsigned long long o = cand[s][tid];
            if (o < k0) k0 = o;
        }
        int idx = (int)(k0 & 0xFFFFFFFFull);
        s_idx[tid] = idx;
        out[OFF_IDX + P0 + tid] = (float)idx;
        atomicAdd(&hist[idx], 1u);
    }
    __syncthreads();

    // ---- q_ste + loss: wave wv handles dims [16wv,16wv+16) for its lane's point ----
    {
        const int ww = lane;
        const int myidx = s_idx[ww];
        const float* eq = emb + (size_t)myidx * DIM + wv * 16;
        float* qb = out + OFF_Q + ((size_t)b * 64 + wv * 16) * 4096 + h * 64 + ww;
        float lsum = 0.f;
#pragma unroll
        for (int q = 0; q < 4; ++q) {
            float4 ev = *(const float4*)(eq + q * 4);
            float4 xv = *(const float4*)&lds_x[ww][wv * 16 + q * 4];
            float d0 = ev.x - xv.x, d1 = ev.y - xv.y, d2 = ev.z - xv.z, d3 = ev.w - xv.w;
            lsum = fmaf(d0, d0, lsum);
            lsum = fmaf(d1, d1, lsum);
            lsum = fmaf(d2, d2, lsum);
            lsum = fmaf(d3, d3, lsum);
            __builtin_nontemporal_store(xv.x + d0, qb + (size_t)(q * 4 + 0) * 4096);
            __builtin_nontemporal_store(xv.y + d1, qb + (size_t)(q * 4 + 1) * 4096);
            __builtin_nontemporal_store(xv.z + d2, qb + (size_t)(q * 4 + 2) * 4096);
            __builtin_nontemporal_store(xv.w + d3, qb + (size_t)(q * 4 + 3) * 4096);
        }
        for (int off = 32; off > 0; off >>= 1) lsum += __shfl_down(lsum, off, 64);
        if (lane == 0) atomicAdd(loss_acc, lsum);
    }

    // ---- one-hot stream: 64 rows x 1024 floats, nontemporal f32x2 ----
    {
        f32x2* enc2 = (f32x2*)(out + OFF_ENC + (unsigned long long)blockIdx.x * 64 * NCODE);
#pragma unroll 8
        for (int i = 0; i < 128; ++i) {
            int j2 = tid + i * 256;
            int pr = j2 >> 9;
            int c2 = j2 & 511;
            int tb = s_idx[pr];
            f32x2 v = {0.f, 0.f};
            if (c2 == (tb >> 1)) { if (tb & 1) v.y = 1.0f; else v.x = 1.0f; }
            __builtin_nontemporal_store(v, &enc2[j2]);
        }
    }
}

// ---------------- finalize: loss scalar + perplexity ----------------
__global__ __launch_bounds__(1024) void vq_finalize(const unsigned int* __restrict__ hist,
                                                    const float* __restrict__ loss_acc,
                                                    float* __restrict__ out) {
    int t = threadIdx.x;
    float c = (float)hist[t];
    float pv = c * (1.0f / (float)NPTS);
    float term = pv * logf(pv + 1e-10f);

    __shared__ float red[16];
    float s = term;
    for (int off = 32; off > 0; off >>= 1) s += __shfl_down(s, off, 64);
    if ((t & 63) == 0) red[t >> 6] = s;
    __syncthreads();
    if (t < 16) {
        float v = red[t];
        for (int off = 8; off > 0; off >>= 1) v += __shfl_down(v, off, 64);
        if (t == 0) {
            out[OFF_PERP] = expf(-v);
            out[OFF_LOSS] = 0.25f * loss_acc[0] * (1.0f / 4194304.0f);
        }
    }
}

extern "C" void kernel_launch(void* const* d_in, const int* in_sizes, int n_in,
                              void* d_out, int out_size, void* d_ws, size_t ws_size,
                              hipStream_t stream) {
    const float* in  = (const float*)d_in[0];   // (16,64,64,64) BCHW
    const float* emb = (const float*)d_in[1];   // (1024,64)
    float* out = (float*)d_out;

    // ws layout: [0..15] loss_acc f32 | [16..1039] hist u32 | [1040..2063] e2 f32
    //            | ehi ushort[65536] | elo ushort[65536]
    float* ws_f = (float*)d_ws;
    float* loss_acc = ws_f;
    unsigned int* hist = (unsigned int*)d_ws + 16;
    float* e2 = ws_f + 16 + NCODE;
    unsigned short* ehi = (unsigned short*)(ws_f + 16 + 2 * NCODE);
    unsigned short* elo = ehi + (size_t)NCODE * DIM;

    (void)hipMemsetAsync(d_ws, 0, (16 + NCODE) * sizeof(float), stream);

    vq_ecvt<<<(NCODE * DIM / 4) / 256, 256, 0, stream>>>(emb, ehi, elo);
    vq_e2<<<NCODE / 256, 256, 0, stream>>>(emb, e2);
    vq_fused<<<NPTS / 64, 256, 0, stream>>>(in, ehi, elo, e2, emb, out, hist, loss_acc);
    vq_finalize<<<1, 1024, 0, stream>>>(hist, loss_acc, out);
}